// Round 9
// baseline (2381.328 us; speedup 1.0000x reference)
//
#include <hip/hip_runtime.h>
#include <cstdint>
#include <cstddef>

typedef __bf16          bf16x8  __attribute__((ext_vector_type(8)));
typedef float           f32x4   __attribute__((ext_vector_type(4)));
typedef unsigned short  u16x8   __attribute__((ext_vector_type(8)));

__device__ __forceinline__ unsigned short f32_bf16_rne(float f) {
  union { float f; unsigned u; } v; v.f = f;
  unsigned u = v.u + 0x7FFFu + ((v.u >> 16) & 1u);
  return (unsigned short)(u >> 16);
}

// ---------------- flat fp32 -> bf16 convert (vectorized, G13) ----------------
__global__ void cvt_f32_bf16(const float* __restrict__ in,
                             unsigned short* __restrict__ out, int n8) {
  int idx = blockIdx.x * 256 + threadIdx.x;
  int stride = gridDim.x * 256;
  for (int i = idx; i < n8; i += stride) {
    float4 a = ((const float4*)in)[2 * (size_t)i];
    float4 b = ((const float4*)in)[2 * (size_t)i + 1];
    u16x8 o;
    o[0] = f32_bf16_rne(a.x); o[1] = f32_bf16_rne(a.y);
    o[2] = f32_bf16_rne(a.z); o[3] = f32_bf16_rne(a.w);
    o[4] = f32_bf16_rne(b.x); o[5] = f32_bf16_rne(b.y);
    o[6] = f32_bf16_rne(b.z); o[7] = f32_bf16_rne(b.w);
    *(u16x8*)(out + (size_t)i * 8) = o;
  }
}

// ------------- beta (H x O, f32) -> betaT (O x H, bf16) transpose ------------
__global__ void cvt_transpose(const float* __restrict__ in,
                              unsigned short* __restrict__ out, int H, int O) {
  __shared__ float tile[32][33];
  int o0 = blockIdx.x * 32, h0 = blockIdx.y * 32;
  int tx = threadIdx.x & 31, ty = threadIdx.x >> 5;
  #pragma unroll
  for (int i = ty; i < 32; i += 8)
    tile[i][tx] = in[(size_t)(h0 + i) * O + (o0 + tx)];
  __syncthreads();
  #pragma unroll
  for (int i = ty; i < 32; i += 8)
    out[(size_t)(o0 + i) * H + (h0 + tx)] = f32_bf16_rne(tile[tx][i]);
}

#define GLOAD(gp, lp)                                                   \
  __builtin_amdgcn_global_load_lds(                                     \
      (const __attribute__((address_space(1))) void*)(gp),              \
      (__attribute__((address_space(3))) void*)(lp), 16, 0, 0)

#define MFMA16 __builtin_amdgcn_mfma_f32_16x16x32_bf16

// ========= 128x256 8-wave GEMM with FUSED W fp32->bf16 conversion ============
// C[m,n] = relu(scale * sum_k A[m,k]*Wf[n,k]) -> bf16.  A: MxK bf16 (y/x),
// Wf: NxK **fp32** (raw input W layer).  R3's proven skeleton (3-slot LDS
// rotation, 1 barrier/K-tile, T2 swizzle, 2M x 4N waves of 64x64) with the B
// staging path replaced by reg-staging + in-register RNE convert (T14):
//   body t: cvt+ds_write B(t+1) [compiler auto-vmcnt: retires B(t+1) loads
//           AND the older A(t+1) gloads -> slot t+1 fully written pre-barrier]
//           gload_lds A(t+2); global_load fp32 B(t+2) -> regs;
//           lgkm(0); s_barrier; ds_read frags(t+1); MFMA(t).
// NO hand-counted vmcnt (R5's bug class is structurally impossible here).
// WAR on slots: 3-deep rotation, reads of a slot finish >= 2 barriers before
// its overwrite (same argument as R3).  Per-XCD: grid x=8 -> XCD = x, the 2MB
// fp32 W panel stays L2-resident for all 32 same-x blocks.

#define BODYF(T, RBC, RBN, FAC, FBC, FAN, FBN)                            \
  do {                                                                    \
    const int t_ = (T);                                                   \
    if (t_ + 1 < NT) {  /* cvt+write B(t+1) -> slot srd */                \
      unsigned short* wB = (unsigned short*)(Bs + srd * 16384);           \
      _Pragma("unroll")                                                   \
      for (int j = 0; j < 4; ++j) {                                       \
        u16x8 o;                                                          \
        f32x4 pa = RBC[2 * j], pb = RBC[2 * j + 1];                       \
        o[0] = f32_bf16_rne(pa[0]); o[1] = f32_bf16_rne(pa[1]);           \
        o[2] = f32_bf16_rne(pa[2]); o[3] = f32_bf16_rne(pa[3]);           \
        o[4] = f32_bf16_rne(pb[0]); o[5] = f32_bf16_rne(pb[1]);           \
        o[6] = f32_bf16_rne(pb[2]); o[7] = f32_bf16_rne(pb[3]);           \
        *(u16x8*)(wB + bwRowOff + ((bc0 + j * 8) ^ bwXor)) = o;           \
      }                                                                   \
    }                                                                     \
    if (t_ + 2 < NT) {                                                    \
      const size_t ko = (size_t)(t_ + 2) * 64;                            \
      __bf16* dA = As + sst * 8192;                                       \
      GLOAD(gA0 + ko, dA + tid * 8);                                      \
      GLOAD(gA1 + ko, dA + 4096 + tid * 8);                               \
      _Pragma("unroll")                                                   \
      for (int j = 0; j < 8; ++j)                                         \
        RBN[j] = *(const f32x4*)(gWf + ko + j * 4);                       \
    }                                                                     \
    asm volatile("s_waitcnt lgkmcnt(0)" ::: "memory");                    \
    __builtin_amdgcn_s_barrier();                                         \
    __builtin_amdgcn_sched_barrier(0);                                    \
    if (t_ + 1 < NT) {                                                    \
      const __bf16* rA = As + srd * 8192;                                 \
      const __bf16* rB = Bs + srd * 16384;                                \
      _Pragma("unroll")                                                   \
      for (int m = 0; m < 4; ++m) {                                       \
        FAN[0][m] = *(const bf16x8*)(rA + aBase + m * 1024 + cc0);        \
        FAN[1][m] = *(const bf16x8*)(rA + aBase + m * 1024 + cc1);        \
      }                                                                   \
      _Pragma("unroll")                                                   \
      for (int n = 0; n < 4; ++n) {                                       \
        FBN[0][n] = *(const bf16x8*)(rB + bBase + n * 1024 + cc0);        \
        FBN[1][n] = *(const bf16x8*)(rB + bBase + n * 1024 + cc1);        \
      }                                                                   \
    }                                                                     \
    __builtin_amdgcn_s_setprio(1);                                        \
    _Pragma("unroll")                                                     \
    for (int kk = 0; kk < 2; ++kk)                                        \
      _Pragma("unroll")                                                   \
      for (int m = 0; m < 4; ++m)                                         \
        _Pragma("unroll")                                                 \
        for (int n = 0; n < 4; ++n)                                       \
          acc[m][n] = MFMA16(FAC[kk][m], FBC[kk][n], acc[m][n], 0, 0, 0); \
    __builtin_amdgcn_s_setprio(0);                                        \
    __builtin_amdgcn_sched_barrier(0);                                    \
    sst = sst + 1 == 3 ? 0 : sst + 1;                                     \
    srd = srd + 1 == 3 ? 0 : srd + 1;                                     \
  } while (0)

__global__ __launch_bounds__(512, 2)
void gemm_fusedW(const unsigned short* __restrict__ A,
                 const float* __restrict__ Wf,
                 unsigned short* __restrict__ Cp, int N, int K, float scale) {
  __shared__ __bf16 As[3 * 128 * 64] __attribute__((aligned(16)));  // 48 KiB
  __shared__ __bf16 Bs[3 * 256 * 64] __attribute__((aligned(16)));  // 96 KiB

  const int tid  = threadIdx.x;
  const int lane = tid & 63;
  const int wave = tid >> 6;      // 0..7
  const int wr   = wave >> 2;     // 0..1 (M)
  const int wc   = wave & 3;      // 0..3 (N)
  const int l16  = lane & 15;
  const int kgrp = lane >> 4;     // 0..3

  const int brow0 = blockIdx.y * 128;
  const int bcol0 = blockIdx.x * 256;   // gridDim.x = 8 = #XCDs

  // frag ds_read addressing (T2): elem = row*64 + (col ^ ((row&7)<<3))
  const int xorv  = (l16 & 7) << 3;
  const int cc0   = (kgrp * 8) ^ xorv;
  const int cc1   = (32 + kgrp * 8) ^ xorv;
  const int aBase = (wr * 64 + l16) * 64;
  const int bBase = (wc * 64 + l16) * 64;

  // A staging (unchanged from R3): 2 gloads of 64 rows, pre-swizzled col
  const int srow = tid >> 3;                              // 0..63
  const int scol = ((tid & 7) * 8) ^ ((srow & 7) << 3);
  const unsigned short* gA0 = A + (size_t)(brow0 +  0 + srow) * K + scol;
  const unsigned short* gA1 = A + (size_t)(brow0 + 64 + srow) * K + scol;

  // B fp32 source: thread covers W row (bcol0 + tid>>1), 32 cols at (tid&1)*32
  const int brow = tid >> 1;             // 0..255
  const int bc0  = (tid & 1) * 32;       // logical col base (fp32 == bf16 idx)
  const float* gWf = Wf + (size_t)(bcol0 + brow) * K + bc0;
  const int bwRowOff = brow * 64;                  // LDS row offset (elems)
  const int bwXor    = (brow & 7) << 3;            // write-side swizzle

  f32x4  acc[4][4] = {};
  bf16x8 faE[2][4], fbE[2][4], faO[2][4], fbO[2][4];
  f32x4  rbE[8], rbO[8];

  const int NT = K >> 6;  // 32 for K=2048 (NT even, >= 3)

  // ---- prologue ----
  {
    GLOAD(gA0, &As[tid * 8]);                  // A(0) -> slot 0
    GLOAD(gA1, &As[4096 + tid * 8]);
    GLOAD(gA0 + 64, &As[8192 + tid * 8]);      // A(1) -> slot 1
    GLOAD(gA1 + 64, &As[8192 + 4096 + tid * 8]);
    #pragma unroll
    for (int j = 0; j < 8; ++j) rbE[j] = *(const f32x4*)(gWf + j * 4);      // B(0)
    #pragma unroll
    for (int j = 0; j < 8; ++j) rbO[j] = *(const f32x4*)(gWf + 64 + j * 4); // B(1)
    // cvt+write B(0) -> slot 0 (compiler waits B(0) regs => A(0),A(1) retired)
    unsigned short* wB = (unsigned short*)Bs;
    #pragma unroll
    for (int j = 0; j < 4; ++j) {
      u16x8 o;
      f32x4 pa = rbE[2 * j], pb = rbE[2 * j + 1];
      o[0] = f32_bf16_rne(pa[0]); o[1] = f32_bf16_rne(pa[1]);
      o[2] = f32_bf16_rne(pa[2]); o[3] = f32_bf16_rne(pa[3]);
      o[4] = f32_bf16_rne(pb[0]); o[5] = f32_bf16_rne(pb[1]);
      o[6] = f32_bf16_rne(pb[2]); o[7] = f32_bf16_rne(pb[3]);
      *(u16x8*)(wB + bwRowOff + ((bc0 + j * 8) ^ bwXor)) = o;
    }
    asm volatile("s_waitcnt lgkmcnt(0)" ::: "memory");
    __builtin_amdgcn_s_barrier();
    __builtin_amdgcn_sched_barrier(0);
    #pragma unroll
    for (int m = 0; m < 4; ++m) {              // frags(0) from slot 0
      faE[0][m] = *(const bf16x8*)(As + aBase + m * 1024 + cc0);
      faE[1][m] = *(const bf16x8*)(As + aBase + m * 1024 + cc1);
    }
    #pragma unroll
    for (int n = 0; n < 4; ++n) {
      fbE[0][n] = *(const bf16x8*)(Bs + bBase + n * 1024 + cc0);
      fbE[1][n] = *(const bf16x8*)(Bs + bBase + n * 1024 + cc1);
    }
  }

  int sst = 2, srd = 1;
  for (int t = 0; t < NT; t += 2) {
    BODYF(t,     rbO, rbE, faE, fbE, faO, fbO);  // cvt B(t+1)=rbO, load B(t+2)->rbE
    BODYF(t + 1, rbE, rbO, faO, fbO, faE, fbE);
  }

  // epilogue: relu(acc*scale) -> bf16. D: col=lane&15, row=(lane>>4)*4+j
  const int crow0 = brow0 + wr * 64 + kgrp * 4;
  const int ccol0 = bcol0 + wc * 64 + l16;
  #pragma unroll
  for (int m = 0; m < 4; ++m)
    #pragma unroll
    for (int n = 0; n < 4; ++n)
      #pragma unroll
      for (int j = 0; j < 4; ++j) {
        float v = acc[m][n][j] * scale;
        v = v > 0.0f ? v : 0.0f;
        Cp[(size_t)(crow0 + m * 16 + j) * N + (ccol0 + n * 16)] = f32_bf16_rne(v);
      }
}

// ---------------- 128x128 m97-structure GEMM (readout only) ------------------
__global__ __launch_bounds__(256)
void gemm_bt_f32(const unsigned short* __restrict__ A,
                 const unsigned short* __restrict__ B,
                 float* __restrict__ C, int N, int K, float scale) {
  __shared__ __bf16 As[128 * 32] __attribute__((aligned(16)));
  __shared__ __bf16 Bs[128 * 32] __attribute__((aligned(16)));

  const int tid  = threadIdx.x;
  const int lane = tid & 63;
  const int wave = tid >> 6;
  const int wr   = wave >> 1, wc = wave & 1;
  const int l16  = lane & 15, kgrp = lane >> 4;

  const int brow0 = blockIdx.y * 128;
  const int bcol0 = blockIdx.x * 128;

  const int offb  = wave * 2048 + lane * 16;
  const int srow  = offb >> 6;
  const int selem = (offb & 63) >> 1;
  const unsigned short* gA0 = A + (size_t)(brow0 + srow) * K + selem;
  const unsigned short* gA1 = A + (size_t)(brow0 + srow + 16) * K + selem;
  const unsigned short* gB0 = B + (size_t)(bcol0 + srow) * K + selem;
  const unsigned short* gB1 = B + (size_t)(bcol0 + srow + 16) * K + selem;
  __bf16* lA0 = &As[wave * 1024];
  __bf16* lA1 = &As[wave * 1024 + 512];
  __bf16* lB0 = &Bs[wave * 1024];
  __bf16* lB1 = &Bs[wave * 1024 + 512];

  f32x4 acc[4][4] = {};
  const int aoff = (wr * 64 + l16) * 32 + kgrp * 8;
  const int boff = (wc * 64 + l16) * 32 + kgrp * 8;

  for (int k0 = 0; k0 < K; k0 += 32) {
    GLOAD(gA0 + k0, lA0);
    GLOAD(gA1 + k0, lA1);
    GLOAD(gB0 + k0, lB0);
    GLOAD(gB1 + k0, lB1);
    asm volatile("s_waitcnt vmcnt(0)" ::: "memory");
    __syncthreads();

    bf16x8 af[4], bfv[4];
    #pragma unroll
    for (int m = 0; m < 4; ++m)
      af[m] = *(const bf16x8*)(As + aoff + m * 16 * 32);
    #pragma unroll
    for (int n = 0; n < 4; ++n)
      bfv[n] = *(const bf16x8*)(Bs + boff + n * 16 * 32);
    #pragma unroll
    for (int m = 0; m < 4; ++m)
      #pragma unroll
      for (int n = 0; n < 4; ++n)
        acc[m][n] = MFMA16(af[m], bfv[n], acc[m][n], 0, 0, 0);
    __syncthreads();
  }

  const int crow0 = brow0 + wr * 64 + kgrp * 4;
  const int ccol0 = bcol0 + wc * 64 + l16;
  #pragma unroll
  for (int m = 0; m < 4; ++m)
    #pragma unroll
    for (int n = 0; n < 4; ++n)
      #pragma unroll
      for (int j = 0; j < 4; ++j)
        C[(size_t)(crow0 + m * 16 + j) * N + (ccol0 + n * 16)] =
            acc[m][n][j] * scale;
}

extern "C" void kernel_launch(void* const* d_in, const int* in_sizes, int n_in,
                              void* d_out, int out_size, void* d_ws, size_t ws_size,
                              hipStream_t stream) {
  const float* x    = (const float*)d_in[0];  // (4096, 2048)
  const float* W    = (const float*)d_in[1];  // (8, 2048, 2048) fp32
  const float* beta = (const float*)d_in[2];  // (2048, 1024)
  float* out = (float*)d_out;                 // (4096, 1024) f32

  const int Bn = 4096, H = 2048, L = 8, O = 1024;

  // ws layout (bf16 as ushort): y0 | y1 | betaT  = 38 MB (W convert fused away)
  unsigned short* y0    = (unsigned short*)d_ws;
  unsigned short* y1    = y0 + (size_t)Bn * H;
  unsigned short* betaT = y1 + (size_t)Bn * H;

  // x -> bf16
  {
    int n8 = Bn * H / 8;
    int grid = (n8 + 255) / 256;
    if (grid > 2048) grid = 2048;
    cvt_f32_bf16<<<grid, 256, 0, stream>>>(x, y0, n8);
  }
  cvt_transpose<<<dim3(O / 32, H / 32), 256, 0, stream>>>(beta, betaT, H, O);

  const float s1 = 0.02209708691207961f;  // 1/sqrt(2048)
  unsigned short* yin = y0;
  unsigned short* yout = y1;
  for (int l = 0; l < L; ++l) {
    gemm_fusedW<<<dim3(H / 256, Bn / 128), 512, 0, stream>>>(
        yin, W + (size_t)l * H * H, yout, H, H, s1);
    unsigned short* t = yin; yin = yout; yout = t;
  }
  gemm_bt_f32<<<dim3(O / 128, Bn / 128), 256, 0, stream>>>(yin, betaT, out, O, H,
                                                           1.0f / 2048.0f);
}

// Round 10
// 408.219 us; speedup vs baseline: 5.8335x; 5.8335x over previous
//
#include <hip/hip_runtime.h>
#include <cstdint>
#include <cstddef>

typedef __bf16          bf16x8  __attribute__((ext_vector_type(8)));
typedef float           f32x4   __attribute__((ext_vector_type(4)));
typedef unsigned short  u16x8   __attribute__((ext_vector_type(8)));

__device__ __forceinline__ unsigned short f32_bf16_rne(float f) {
  union { float f; unsigned u; } v; v.f = f;
  unsigned u = v.u + 0x7FFFu + ((v.u >> 16) & 1u);
  return (unsigned short)(u >> 16);
}

// ---------------- flat fp32 -> bf16 convert (vectorized, G13) ----------------
__global__ void cvt_f32_bf16(const float* __restrict__ in,
                             unsigned short* __restrict__ out, int n8) {
  int idx = blockIdx.x * 256 + threadIdx.x;
  int stride = gridDim.x * 256;
  for (int i = idx; i < n8; i += stride) {
    float4 a = ((const float4*)in)[2 * (size_t)i];
    float4 b = ((const float4*)in)[2 * (size_t)i + 1];
    u16x8 o;
    o[0] = f32_bf16_rne(a.x); o[1] = f32_bf16_rne(a.y);
    o[2] = f32_bf16_rne(a.z); o[3] = f32_bf16_rne(a.w);
    o[4] = f32_bf16_rne(b.x); o[5] = f32_bf16_rne(b.y);
    o[6] = f32_bf16_rne(b.z); o[7] = f32_bf16_rne(b.w);
    *(u16x8*)(out + (size_t)i * 8) = o;
  }
}

// ------------- beta (H x O, f32) -> betaT (O x H, bf16) transpose ------------
__global__ void cvt_transpose(const float* __restrict__ in,
                              unsigned short* __restrict__ out, int H, int O) {
  __shared__ float tile[32][33];
  int o0 = blockIdx.x * 32, h0 = blockIdx.y * 32;
  int tx = threadIdx.x & 31, ty = threadIdx.x >> 5;
  #pragma unroll
  for (int i = ty; i < 32; i += 8)
    tile[i][tx] = in[(size_t)(h0 + i) * O + (o0 + tx)];
  __syncthreads();
  #pragma unroll
  for (int i = ty; i < 32; i += 8)
    out[(size_t)(o0 + i) * H + (h0 + tx)] = f32_bf16_rne(tile[tx][i]);
}

#define GLOAD(gp, lp)                                                   \
  __builtin_amdgcn_global_load_lds(                                     \
      (const __attribute__((address_space(1))) void*)(gp),              \
      (__attribute__((address_space(3))) void*)(lp), 16, 0, 0)

#define MFMA16 __builtin_amdgcn_mfma_f32_16x16x32_bf16

// ======== 128x256 8-wave GEMM, m201-style 2-phase-per-K-tile schedule ========
// C[m,n] = relu(scale * sum_k A[m,k]*B[n,k]) -> bf16.   A: MxK, B: NxK bf16.
// Geometry = R3's proven 2M x 4N waves of 64x64, 3-slot LDS rotation, T2
// swizzle both-sides, gridDim.x == 8 == #XCDs (B panel per XCD L2).
// Schedule = m201 phase template: per K-tile t, TWO phases, each
//   { 8 ds_read (frags of tile t, kk half)  ||  3 stage-gloads for tile t+2
//     -> sched_barrier -> s_barrier -> lgkmcnt(0) -> sched_barrier
//     -> setprio(1) -> 16 MFMA -> setprio(0) -> s_barrier }
// Frags consumed in-phase (no reg double-buffer: -64 VGPR vs R3).
// Counted vmcnt(6) ONCE per K-tile (end of P1): in-flight = tiles t+1,t+2
// (12 loads) -> retires tile t+1's 6 before the barrier preceding its reads.
// Tail: vmcnt(0) at t==NT-2.  WAR on slot (t+2)%3 = (t-1)%3: tile t-1's reads
// were lgkm(0)-drained before MFMA(t-1,P1), hence before that phase's final
// barrier, which precedes this body's stage issue.

__global__ __launch_bounds__(512, 2)
void gemm8p(const unsigned short* __restrict__ A,
            const unsigned short* __restrict__ B,
            unsigned short* __restrict__ Cp, int N, int K, float scale) {
  __shared__ __bf16 As[3 * 128 * 64] __attribute__((aligned(16)));  // 48 KiB
  __shared__ __bf16 Bs[3 * 256 * 64] __attribute__((aligned(16)));  // 96 KiB

  const int tid  = threadIdx.x;
  const int lane = tid & 63;
  const int wave = tid >> 6;      // 0..7
  const int wr   = wave >> 2;     // 0..1 (M)
  const int wc   = wave & 3;      // 0..3 (N)
  const int l16  = lane & 15;
  const int kgrp = lane >> 4;     // 0..3

  const int brow0 = blockIdx.y * 128;
  const int bcol0 = blockIdx.x * 256;   // gridDim.x = 8 = #XCDs

  // frag ds_read addressing (T2): elem = row*64 + (col ^ ((row&7)<<3))
  const int xorv  = (l16 & 7) << 3;
  const int cc0   = (kgrp * 8) ^ xorv;
  const int cc1   = (32 + kgrp * 8) ^ xorv;
  const int aBase = (wr * 64 + l16) * 64;
  const int bBase = (wc * 64 + l16) * 64;

  // staging: each GLOAD line = 64 rows x 64 elems (8 KB), thread covers 16 B;
  // global col pre-swizzled so swizzled ds_read sees logical data (rule 21).
  const int srow = tid >> 3;                              // 0..63
  const int scol = ((tid & 7) * 8) ^ ((srow & 7) << 3);   // pre-swizzled col
  const unsigned short* gA0 = A + (size_t)(brow0 +   0 + srow) * K + scol;
  const unsigned short* gA1 = A + (size_t)(brow0 +  64 + srow) * K + scol;
  const unsigned short* gB0 = B + (size_t)(bcol0 +   0 + srow) * K + scol;
  const unsigned short* gB1 = B + (size_t)(bcol0 +  64 + srow) * K + scol;
  const unsigned short* gB2 = B + (size_t)(bcol0 + 128 + srow) * K + scol;
  const unsigned short* gB3 = B + (size_t)(bcol0 + 192 + srow) * K + scol;

  f32x4 acc[4][4] = {};

  const int NT = K >> 6;  // 32 for K=2048 (NT >= 3)

  // ---- prologue: stage tiles 0 -> slot0, 1 -> slot1; wait tile0
  {
    GLOAD(gA0, &As[0 * 4096 + tid * 8]);
    GLOAD(gA1, &As[1 * 4096 + tid * 8]);
    GLOAD(gB0, &Bs[0 * 4096 + tid * 8]);
    GLOAD(gB1, &Bs[1 * 4096 + tid * 8]);
    GLOAD(gB2, &Bs[2 * 4096 + tid * 8]);
    GLOAD(gB3, &Bs[3 * 4096 + tid * 8]);
    GLOAD(gA0 + 64, &As[8192 + 0 * 4096 + tid * 8]);
    GLOAD(gA1 + 64, &As[8192 + 1 * 4096 + tid * 8]);
    GLOAD(gB0 + 64, &Bs[16384 + 0 * 4096 + tid * 8]);
    GLOAD(gB1 + 64, &Bs[16384 + 1 * 4096 + tid * 8]);
    GLOAD(gB2 + 64, &Bs[16384 + 2 * 4096 + tid * 8]);
    GLOAD(gB3 + 64, &Bs[16384 + 3 * 4096 + tid * 8]);
    asm volatile("s_waitcnt vmcnt(6)" ::: "memory");
    __builtin_amdgcn_s_barrier();
    __builtin_amdgcn_sched_barrier(0);
  }

  int srd = 0, sst = 2;   // tile t lives in slot t%3; stage t+2 -> (t+2)%3
  for (int t = 0; t < NT; ++t) {
    const __bf16* rA = As + srd * 8192;
    const __bf16* rB = Bs + srd * 16384;
    __bf16* dA = As + sst * 8192;
    __bf16* dB = Bs + sst * 16384;
    const bool stg = (t + 2 < NT);
    const size_t ko = (size_t)(t + 2) * 64;

    // ---------------- phase 0 (kk = 0) ----------------
    {
      bf16x8 fa[4], fb[4];
      #pragma unroll
      for (int m = 0; m < 4; ++m)
        fa[m] = *(const bf16x8*)(rA + aBase + m * 1024 + cc0);
      #pragma unroll
      for (int n = 0; n < 4; ++n)
        fb[n] = *(const bf16x8*)(rB + bBase + n * 1024 + cc0);
      if (stg) {
        GLOAD(gA0 + ko, dA + 0 * 4096 + tid * 8);
        GLOAD(gA1 + ko, dA + 1 * 4096 + tid * 8);
        GLOAD(gB0 + ko, dB + 0 * 4096 + tid * 8);
      }
      __builtin_amdgcn_sched_barrier(0);
      __builtin_amdgcn_s_barrier();
      asm volatile("s_waitcnt lgkmcnt(0)" ::: "memory");
      __builtin_amdgcn_sched_barrier(0);
      __builtin_amdgcn_s_setprio(1);
      #pragma unroll
      for (int m = 0; m < 4; ++m)
        #pragma unroll
        for (int n = 0; n < 4; ++n)
          acc[m][n] = MFMA16(fa[m], fb[n], acc[m][n], 0, 0, 0);
      __builtin_amdgcn_s_setprio(0);
      __builtin_amdgcn_sched_barrier(0);
      __builtin_amdgcn_s_barrier();
    }

    // ---------------- phase 1 (kk = 1) ----------------
    {
      bf16x8 fa[4], fb[4];
      #pragma unroll
      for (int m = 0; m < 4; ++m)
        fa[m] = *(const bf16x8*)(rA + aBase + m * 1024 + cc1);
      #pragma unroll
      for (int n = 0; n < 4; ++n)
        fb[n] = *(const bf16x8*)(rB + bBase + n * 1024 + cc1);
      if (stg) {
        GLOAD(gB1 + ko, dB + 1 * 4096 + tid * 8);
        GLOAD(gB2 + ko, dB + 2 * 4096 + tid * 8);
        GLOAD(gB3 + ko, dB + 3 * 4096 + tid * 8);
        asm volatile("s_waitcnt vmcnt(6)" ::: "memory");
      } else if (t == NT - 2) {
        asm volatile("s_waitcnt vmcnt(0)" ::: "memory");
      }
      __builtin_amdgcn_sched_barrier(0);
      __builtin_amdgcn_s_barrier();
      asm volatile("s_waitcnt lgkmcnt(0)" ::: "memory");
      __builtin_amdgcn_sched_barrier(0);
      __builtin_amdgcn_s_setprio(1);
      #pragma unroll
      for (int m = 0; m < 4; ++m)
        #pragma unroll
        for (int n = 0; n < 4; ++n)
          acc[m][n] = MFMA16(fa[m], fb[n], acc[m][n], 0, 0, 0);
      __builtin_amdgcn_s_setprio(0);
      __builtin_amdgcn_sched_barrier(0);
      __builtin_amdgcn_s_barrier();
    }

    srd = srd + 1 == 3 ? 0 : srd + 1;
    sst = sst + 1 == 3 ? 0 : sst + 1;
  }

  // epilogue: relu(acc*scale) -> bf16. D: col=lane&15, row=(lane>>4)*4+j
  const int crow0 = brow0 + wr * 64 + kgrp * 4;
  const int ccol0 = bcol0 + wc * 64 + l16;
  #pragma unroll
  for (int m = 0; m < 4; ++m)
    #pragma unroll
    for (int n = 0; n < 4; ++n)
      #pragma unroll
      for (int j = 0; j < 4; ++j) {
        float v = acc[m][n][j] * scale;
        v = v > 0.0f ? v : 0.0f;
        Cp[(size_t)(crow0 + m * 16 + j) * N + (ccol0 + n * 16)] = f32_bf16_rne(v);
      }
}

// ---------------- 128x128 m97-structure GEMM (readout only) ------------------
__global__ __launch_bounds__(256)
void gemm_bt_f32(const unsigned short* __restrict__ A,
                 const unsigned short* __restrict__ B,
                 float* __restrict__ C, int N, int K, float scale) {
  __shared__ __bf16 As[128 * 32] __attribute__((aligned(16)));
  __shared__ __bf16 Bs[128 * 32] __attribute__((aligned(16)));

  const int tid  = threadIdx.x;
  const int lane = tid & 63;
  const int wave = tid >> 6;
  const int wr   = wave >> 1, wc = wave & 1;
  const int l16  = lane & 15, kgrp = lane >> 4;

  const int brow0 = blockIdx.y * 128;
  const int bcol0 = blockIdx.x * 128;

  const int offb  = wave * 2048 + lane * 16;
  const int srow  = offb >> 6;
  const int selem = (offb & 63) >> 1;
  const unsigned short* gA0 = A + (size_t)(brow0 + srow) * K + selem;
  const unsigned short* gA1 = A + (size_t)(brow0 + srow + 16) * K + selem;
  const unsigned short* gB0 = B + (size_t)(bcol0 + srow) * K + selem;
  const unsigned short* gB1 = B + (size_t)(bcol0 + srow + 16) * K + selem;
  __bf16* lA0 = &As[wave * 1024];
  __bf16* lA1 = &As[wave * 1024 + 512];
  __bf16* lB0 = &Bs[wave * 1024];
  __bf16* lB1 = &Bs[wave * 1024 + 512];

  f32x4 acc[4][4] = {};
  const int aoff = (wr * 64 + l16) * 32 + kgrp * 8;
  const int boff = (wc * 64 + l16) * 32 + kgrp * 8;

  for (int k0 = 0; k0 < K; k0 += 32) {
    GLOAD(gA0 + k0, lA0);
    GLOAD(gA1 + k0, lA1);
    GLOAD(gB0 + k0, lB0);
    GLOAD(gB1 + k0, lB1);
    asm volatile("s_waitcnt vmcnt(0)" ::: "memory");
    __syncthreads();

    bf16x8 af[4], bfv[4];
    #pragma unroll
    for (int m = 0; m < 4; ++m)
      af[m] = *(const bf16x8*)(As + aoff + m * 16 * 32);
    #pragma unroll
    for (int n = 0; n < 4; ++n)
      bfv[n] = *(const bf16x8*)(Bs + boff + n * 16 * 32);
    #pragma unroll
    for (int m = 0; m < 4; ++m)
      #pragma unroll
      for (int n = 0; n < 4; ++n)
        acc[m][n] = MFMA16(af[m], bfv[n], acc[m][n], 0, 0, 0);
    __syncthreads();
  }

  const int crow0 = brow0 + wr * 64 + kgrp * 4;
  const int ccol0 = bcol0 + wc * 64 + l16;
  #pragma unroll
  for (int m = 0; m < 4; ++m)
    #pragma unroll
    for (int n = 0; n < 4; ++n)
      #pragma unroll
      for (int j = 0; j < 4; ++j)
        C[(size_t)(crow0 + m * 16 + j) * N + (ccol0 + n * 16)] =
            acc[m][n][j] * scale;
}

extern "C" void kernel_launch(void* const* d_in, const int* in_sizes, int n_in,
                              void* d_out, int out_size, void* d_ws, size_t ws_size,
                              hipStream_t stream) {
  const float* x    = (const float*)d_in[0];  // (4096, 2048)
  const float* W    = (const float*)d_in[1];  // (8, 2048, 2048)
  const float* beta = (const float*)d_in[2];  // (2048, 1024)
  float* out = (float*)d_out;                 // (4096, 1024) f32

  const int Bn = 4096, H = 2048, L = 8, O = 1024;

  // ws layout (bf16 as ushort): y0 | y1 | Wb[8 layers] | betaT  = 105 MB
  unsigned short* y0    = (unsigned short*)d_ws;
  unsigned short* y1    = y0 + (size_t)Bn * H;
  unsigned short* Wb    = y1 + (size_t)Bn * H;
  unsigned short* betaT = Wb + (size_t)L * H * H;

  // all 8 W layers -> bf16 in ONE kernel
  {
    int n8 = L * H * H / 8;
    cvt_f32_bf16<<<2048, 256, 0, stream>>>(W, Wb, n8);
  }
  // x -> bf16
  {
    int n8 = Bn * H / 8;
    int grid = (n8 + 255) / 256;
    if (grid > 2048) grid = 2048;
    cvt_f32_bf16<<<grid, 256, 0, stream>>>(x, y0, n8);
  }
  cvt_transpose<<<dim3(O / 32, H / 32), 256, 0, stream>>>(beta, betaT, H, O);

  const float s1 = 0.02209708691207961f;  // 1/sqrt(2048)
  unsigned short* yin = y0;
  unsigned short* yout = y1;
  for (int l = 0; l < L; ++l) {
    gemm8p<<<dim3(H / 256, Bn / 128), 512, 0, stream>>>(
        yin, Wb + (size_t)l * H * H, yout, H, H, s1);
    unsigned short* t = yin; yin = yout; yout = t;
  }
  gemm_bt_f32<<<dim3(O / 128, Bn / 128), 256, 0, stream>>>(yin, betaT, out, O, H,
                                                           1.0f / 2048.0f);
}